// Round 1
// baseline (336.222 us; speedup 1.0000x reference)
//
#include <hip/hip_runtime.h>
#include <hip/hip_bf16.h>

#define N_PIX 196608
#define KNN 32
#define BATCH 8
// CHANNELS = 4 (float4)

// ws layout:
//   [0, N_PIX*32*4)                      : xs  = x transposed to (N,B,C) * inv_rowsum[n]
//   [XS_BYTES, XS_BYTES + N_PIX*4)       : inv_rowsum
//   [XS_BYTES + RS_BYTES, +4)            : int flag (1 = inds are int64, 0 = int32)
#define XS_BYTES ((size_t)N_PIX * 32 * 4)
#define RS_BYTES ((size_t)N_PIX * 4)

// Detect whether inds buffer is int64 (odd 32-bit words of first 64 entries all zero)
__global__ void k_detect(const unsigned int* __restrict__ inds_u32, int* __restrict__ flag) {
    unsigned int v = inds_u32[threadIdx.x * 2 + 1];
    unsigned long long b = __ballot(v != 0);
    if (threadIdx.x == 0) *flag = (b == 0ULL) ? 1 : 0;
}

// inv_rowsum[n] = 1 / sum_k kernel_k[n,k]; 8 lanes per row, float4 per lane.
__global__ __launch_bounds__(256) void k_rowsum(const float* __restrict__ kern,
                                                float* __restrict__ inv_rs) {
    int t = blockIdx.x * 256 + threadIdx.x;          // t in [0, N_PIX*8)
    const float4* kv = reinterpret_cast<const float4*>(kern);
    float4 v = kv[t];                                // fully coalesced
    float s = v.x + v.y + v.z + v.w;
    s += __shfl_xor(s, 1);
    s += __shfl_xor(s, 2);
    s += __shfl_xor(s, 4);
    if ((t & 7) == 0) inv_rs[t >> 3] = 1.0f / s;
}

// xs[n, b, c] = x[b, n, c] * inv_rs[n]   (one 128B line per source pixel)
__global__ __launch_bounds__(256) void k_scale_transpose(const float* __restrict__ x,
                                                         const float* __restrict__ inv_rs,
                                                         float* __restrict__ xs) {
    __shared__ float4 tile[32][9];                   // +1 pad to break bank conflicts
    int n0 = blockIdx.x * 32;
    int tid = threadIdx.x;
    int b = tid >> 5, i = tid & 31;
    const float4* xv = reinterpret_cast<const float4*>(x);
    float4 v = xv[(size_t)b * N_PIX + n0 + i];       // coalesced read
    float r = inv_rs[n0 + i];
    v.x *= r; v.y *= r; v.z *= r; v.w *= r;
    tile[i][b] = v;
    __syncthreads();
    int row = tid >> 3, bb = tid & 7;
    float4* xsv = reinterpret_cast<float4*>(xs);
    xsv[(size_t)(n0 + row) * 8 + bb] = tile[row][bb]; // block writes 4KB contiguous
}

// out[b,n,:] = sum_k kern[n,k] * xs[j(n,k), b, :]
template <typename IdxT>
__device__ __forceinline__ void main_body(int n, const float* __restrict__ kern,
                                          const IdxT* __restrict__ ip,
                                          const float4* __restrict__ xsv,
                                          float* __restrict__ out) {
    float4 acc[BATCH];
#pragma unroll
    for (int b = 0; b < BATCH; ++b) acc[b] = make_float4(0.f, 0.f, 0.f, 0.f);

    float4 wrow[8];
    const float4* kv = reinterpret_cast<const float4*>(kern) + (size_t)n * 8;
#pragma unroll
    for (int q = 0; q < 8; ++q) wrow[q] = kv[q];
    const float* wf = reinterpret_cast<const float*>(wrow);

#pragma unroll 4
    for (int k = 0; k < KNN; ++k) {
        int j = (int)ip[k];
        float w = wf[k];
        const float4* src = xsv + (size_t)j * 8;     // one aligned 128B line
#pragma unroll
        for (int b = 0; b < BATCH; ++b) {
            float4 s = src[b];
            acc[b].x = fmaf(w, s.x, acc[b].x);
            acc[b].y = fmaf(w, s.y, acc[b].y);
            acc[b].z = fmaf(w, s.z, acc[b].z);
            acc[b].w = fmaf(w, s.w, acc[b].w);
        }
    }
    float4* ov = reinterpret_cast<float4*>(out);
#pragma unroll
    for (int b = 0; b < BATCH; ++b) ov[(size_t)b * N_PIX + n] = acc[b];
}

__global__ __launch_bounds__(256) void k_main(const float* __restrict__ kern,
                                              const void* __restrict__ inds,
                                              const float* __restrict__ xs,
                                              const int* __restrict__ flag,
                                              float* __restrict__ out) {
    int n = blockIdx.x * 256 + threadIdx.x;
    const float4* xsv = reinterpret_cast<const float4*>(xs);
    if (*flag) {
        const long long* ip = reinterpret_cast<const long long*>(inds) + (size_t)n * KNN;
        main_body<long long>(n, kern, ip, xsv, out);
    } else {
        const int* ip = reinterpret_cast<const int*>(inds) + (size_t)n * KNN;
        main_body<int>(n, kern, ip, xsv, out);
    }
}

extern "C" void kernel_launch(void* const* d_in, const int* in_sizes, int n_in,
                              void* d_out, int out_size, void* d_ws, size_t ws_size,
                              hipStream_t stream) {
    const float* x    = (const float*)d_in[0];
    const float* kern = (const float*)d_in[1];
    const void*  inds = d_in[2];
    float* out = (float*)d_out;

    float* xs     = (float*)d_ws;
    float* inv_rs = (float*)((char*)d_ws + XS_BYTES);
    int*   flag   = (int*)((char*)d_ws + XS_BYTES + RS_BYTES);

    k_detect<<<1, 64, 0, stream>>>((const unsigned int*)inds, flag);
    k_rowsum<<<(N_PIX * 8) / 256, 256, 0, stream>>>(kern, inv_rs);
    k_scale_transpose<<<N_PIX / 32, 256, 0, stream>>>(x, inv_rs, xs);
    k_main<<<N_PIX / 256, 256, 0, stream>>>(kern, inds, xs, flag, out);
}

// Round 3
// 209.195 us; speedup vs baseline: 1.6072x; 1.6072x over previous
//
#include <hip/hip_runtime.h>
#include <hip/hip_bf16.h>

#define N_PIX 196608
#define KNN 32
#define BATCH 8
// CHANNELS = 4 (float4)

// ws layout:
//   [0, N_PIX*32*4)                : xs = x transposed to (N,B,C) * inv_rowsum[n]
//   [XS_BYTES, +4)                 : int flag (1 = inds are int64, 0 = int32)
#define XS_BYTES ((size_t)N_PIX * 32 * 4)

// Detect whether inds buffer is int64 (odd 32-bit words of first 64 entries all zero)
__global__ void k_detect(const unsigned int* __restrict__ inds_u32, int* __restrict__ flag) {
    unsigned int v = inds_u32[threadIdx.x * 2 + 1];
    unsigned long long b = __ballot(v != 0);
    if (threadIdx.x == 0) *flag = (b == 0ULL) ? 1 : 0;
}

// Fused: rowsum + scale + transpose.  Block handles 32 pixels.
// xs[n, b, c] = x[b, n, c] / rowsum[n]   (one 128B line per source pixel)
__global__ __launch_bounds__(256) void k_prep(const float* __restrict__ x,
                                              const float* __restrict__ kern,
                                              float* __restrict__ xs) {
    __shared__ float s_inv[32];
    __shared__ float4 tile[32][9];                   // +1 pad to break bank conflicts
    int n0 = blockIdx.x * 32;
    int t = threadIdx.x;

    // rowsum: 8 lanes per pixel, float4 each
    const float4* kv = reinterpret_cast<const float4*>(kern);
    float4 v = kv[(size_t)(n0 + (t >> 3)) * 8 + (t & 7)];
    float s = v.x + v.y + v.z + v.w;
    s += __shfl_xor(s, 1);
    s += __shfl_xor(s, 2);
    s += __shfl_xor(s, 4);
    if ((t & 7) == 0) s_inv[t >> 3] = 1.0f / s;
    __syncthreads();

    // scale + stage transpose
    int b = t >> 5, i = t & 31;
    const float4* xv = reinterpret_cast<const float4*>(x);
    float4 u = xv[(size_t)b * N_PIX + n0 + i];       // coalesced read
    float r = s_inv[i];
    u.x *= r; u.y *= r; u.z *= r; u.w *= r;
    tile[i][b] = u;
    __syncthreads();

    int row = t >> 3, bb = t & 7;
    reinterpret_cast<float4*>(xs)[(size_t)(n0 + row) * 8 + bb] = tile[row][bb];
}

// Thread per (n, b): acc[n,b,:] = sum_k kern[n,k] * xs[j(n,k), b, :]
// Lanes 0..7 of each 8-lane group share n (and so j) -> one coalesced 128B
// segment per group per gather instruction.
template <typename IdxT>
__device__ __forceinline__ void main_body(int n, int b, const float* __restrict__ kern,
                                          const IdxT* __restrict__ ip,
                                          const float4* __restrict__ xsv,
                                          float4* __restrict__ ov) {
    const float4* wv = reinterpret_cast<const float4*>(kern) + (size_t)n * 8;
    float4 acc = make_float4(0.f, 0.f, 0.f, 0.f);

#pragma unroll
    for (int k0 = 0; k0 < KNN; k0 += 8) {
        // load 8 (j, w) for this strip; broadcast within 8-lane group
        int j[8];
#pragma unroll
        for (int u = 0; u < 8; ++u) j[u] = (int)ip[k0 + u];
        float4 wa = wv[k0 >> 2];
        float4 wb = wv[(k0 >> 2) + 1];
        float w[8] = {wa.x, wa.y, wa.z, wa.w, wb.x, wb.y, wb.z, wb.w};

        // 8 independent gathers in flight
        float4 sv[8];
#pragma unroll
        for (int u = 0; u < 8; ++u) sv[u] = xsv[(size_t)j[u] * 8 + b];
#pragma unroll
        for (int u = 0; u < 8; ++u) {
            acc.x = fmaf(w[u], sv[u].x, acc.x);
            acc.y = fmaf(w[u], sv[u].y, acc.y);
            acc.z = fmaf(w[u], sv[u].z, acc.z);
            acc.w = fmaf(w[u], sv[u].w, acc.w);
        }
    }
    ov[(size_t)b * N_PIX + n] = acc;
}

__global__ __launch_bounds__(256) void k_main(const float* __restrict__ kern,
                                              const void* __restrict__ inds,
                                              const float* __restrict__ xs,
                                              const int* __restrict__ flag,
                                              float* __restrict__ out) {
    int tid = blockIdx.x * 256 + threadIdx.x;        // [0, N_PIX*8)
    int n = tid >> 3;
    int b = tid & 7;
    const float4* xsv = reinterpret_cast<const float4*>(xs);
    float4* ov = reinterpret_cast<float4*>(out);
    if (*flag) {
        const long long* ip = reinterpret_cast<const long long*>(inds) + (size_t)n * KNN;
        main_body<long long>(n, b, kern, ip, xsv, ov);
    } else {
        const int* ip = reinterpret_cast<const int*>(inds) + (size_t)n * KNN;
        main_body<int>(n, b, kern, ip, xsv, ov);
    }
}

extern "C" void kernel_launch(void* const* d_in, const int* in_sizes, int n_in,
                              void* d_out, int out_size, void* d_ws, size_t ws_size,
                              hipStream_t stream) {
    const float* x    = (const float*)d_in[0];
    const float* kern = (const float*)d_in[1];
    const void*  inds = d_in[2];
    float* out = (float*)d_out;

    float* xs   = (float*)d_ws;
    int*   flag = (int*)((char*)d_ws + XS_BYTES);

    k_detect<<<1, 64, 0, stream>>>((const unsigned int*)inds, flag);
    k_prep<<<N_PIX / 32, 256, 0, stream>>>(x, kern, xs);
    k_main<<<(N_PIX * BATCH) / 256, 256, 0, stream>>>(kern, inds, xs, flag, out);
}